// Round 2
// baseline (409.280 us; speedup 1.0000x reference)
//
#include <hip/hip_runtime.h>
#include <hip/hip_bf16.h>

// out[4096,4096] = x[4096,4096]fp32 @ dequant(int4 W)[4096,4096] + bias
// Algorithm (R2):
//   W' = 128 + w  (exact bf16: 0x4300 + nibble), MFMA computes
//   S_g = sum_{k in g} (xh+xl)[m,k] * W'[k,n]  in fp32 accum; fold:
//   acc += s[g,n]*S_g - s[g,n]*(129+z[g,n]) * R_g[m],  R_g = rowsum of x over group.
//   B-fragments come straight from qweight words (1 int32 = one 8-elem k-run),
//   unpacked in-register: no W LDS, no W barrier.
// Schedule: T3-minimum 2-phase — A hi/lo double-buffered LDS (64KB, 2 blocks/CU),
//   stage(t+1)+loadq(t+1) at tile start, ONE __syncthreads per K-tile at end.

#define K_DIM 4096
#define N_DIM 4096
#define M_DIM 4096
#define BM 128
#define BN 128
#define BK 64
#define NGROUPS 32

typedef __attribute__((ext_vector_type(8))) short s8v;      // 8 bf16 = 4 VGPR
typedef __attribute__((ext_vector_type(4))) float f4v;
typedef __attribute__((ext_vector_type(4))) unsigned int u4v;
typedef __attribute__((ext_vector_type(2))) unsigned int u2v;
typedef __attribute__((ext_vector_type(4))) float float4v;

typedef __attribute__((address_space(3))) void LDSV;
typedef const __attribute__((address_space(1))) void GLBV;

__device__ __forceinline__ void glds16(const void* g, void* l) {
    __builtin_amdgcn_global_load_lds((GLBV*)g, (LDSV*)l, 16, 0, 0);
}

// nibble j of qq -> bf16(128+nib) halfword; two per dword, exact.
__device__ __forceinline__ s8v unpackB(unsigned int qq) {
    u4v d;
    d[0] = 0x43004300u + (qq & 15u) + ((qq & 0xF0u) << 12);
    d[1] = 0x43004300u + ((qq >> 8) & 15u) + ((qq & 0xF000u) << 4);
    d[2] = 0x43004300u + ((qq >> 16) & 15u) + ((qq & 0xF00000u) >> 4);
    d[3] = 0x43004300u + ((qq >> 24) & 15u) + ((qq >> 28) << 16);
    return __builtin_bit_cast(s8v, d);
}

// ---- prologue: split x into truncated bf16 hi+lo AND per-group rowsums -----
__global__ __launch_bounds__(256) void split_rs(const float* __restrict__ x,
                                                unsigned short* __restrict__ xh,
                                                unsigned short* __restrict__ xl,
                                                float* __restrict__ rs) {
    const int m = blockIdx.x;
    const int tid = threadIdx.x;
    const size_t base = (size_t)m * K_DIM;
#pragma unroll
    for (int it = 0; it < 4; ++it) {
        const int i = it * 1024 + tid * 4;
        float4v v = *(const float4v*)(x + base + i);
        unsigned int hb[4], lb[4];
        float s = 0.f;
#pragma unroll
        for (int j = 0; j < 4; j++) {
            unsigned int b = __float_as_uint(v[j]);
            unsigned int h = b & 0xFFFF0000u;
            hb[j] = h;
            lb[j] = __float_as_uint(v[j] - __uint_as_float(h));
            s += v[j];
        }
        u2v hv = {(hb[0] >> 16) | hb[1], (hb[2] >> 16) | hb[3]};
        u2v lv = {(lb[0] >> 16) | (lb[1] & 0xFFFF0000u),
                  (lb[2] >> 16) | (lb[3] & 0xFFFF0000u)};
        *(u2v*)(xh + base + i) = hv;
        *(u2v*)(xl + base + i) = lv;
        // group = 128 floats = 32 consecutive threads (within one 32-lane half)
        s += __shfl_xor(s, 1);
        s += __shfl_xor(s, 2);
        s += __shfl_xor(s, 4);
        s += __shfl_xor(s, 8);
        s += __shfl_xor(s, 16);
        if ((tid & 31) == 0) rs[(size_t)(it * 8 + (tid >> 5)) * K_DIM + m] = s;
    }
}

// ---------------- main GEMM --------------------------------------------------
__global__ __launch_bounds__(256, 2) void gemm_q4(
    const unsigned short* __restrict__ xh, const unsigned short* __restrict__ xl,
    const int* __restrict__ qw, const int* __restrict__ qz,
    const float* __restrict__ scales, const float* __restrict__ rs,
    const float* __restrict__ bias, float* __restrict__ out) {
    __shared__ __align__(16) unsigned short AH[2][BM * BK];  // 32 KB
    __shared__ __align__(16) unsigned short AL[2][BM * BK];  // 32 KB

    const int tid = threadIdx.x;
    const int lane = tid & 63;
    const int wid = tid >> 6;

    // bijective XCD swizzle (1024 wgs, 8 XCDs)
    const int bid = blockIdx.x;
    const int wg = ((bid & 7) << 7) + (bid >> 3);
    const int bm = (wg >> 5) << 7;
    const int bn = (wg & 31) << 7;

    const int wr = ((wid >> 1) & 1) << 6;
    const int wc = (wid & 1) << 6;

    const f4v z4 = {0.f, 0.f, 0.f, 0.f};
    f4v acc[4][4];
    f4v S[4][4];
#pragma unroll
    for (int i = 0; i < 4; i++)
#pragma unroll
        for (int j = 0; j < 4; j++) acc[i][j] = z4;

    // ---- A staging (glds, pre-swizzled source; identical to verified R1) ----
    const int arow = lane >> 3;
    const int aswz = ((lane & 7) ^ arow) << 3;
    const size_t a_gbase = (size_t)(bm + wid * 32 + arow) * K_DIM + aswz;

    // ---- fragment / q addressing ----
    const int frow = lane & 15;
    const int fkq = lane >> 4;           // 0..3 -> kk offset within K=32 step
    const int fk16 = fkq << 4;           // k byte offset within a 64-elem row
    const int qcol = bn + wc + frow;     // ni=0 column
    const int* qbase = qw + (size_t)fkq * N_DIM + qcol;
    const int zsh = (qcol & 7) * 4;
    const int row00 = bm + wr + ((lane >> 4) << 2);

    int qcur[8], qnxt[8];

    auto stage = [&](int kt, int b) {
        const unsigned short* gh = xh + a_gbase + kt * BK;
        const unsigned short* gl = xl + a_gbase + kt * BK;
        unsigned short* hd = &AH[b][(wid * 32) * BK];
        unsigned short* ld_ = &AL[b][(wid * 32) * BK];
#pragma unroll
        for (int i = 0; i < 4; i++) {
            glds16(gh + i * 8 * K_DIM, hd + i * 8 * BK);
            glds16(gl + i * 8 * K_DIM, ld_ + i * 8 * BK);
        }
    };
    auto loadq = [&](int* dst, int kt) {
#pragma unroll
        for (int ks = 0; ks < 2; ks++)
#pragma unroll
            for (int ni = 0; ni < 4; ni++)
                dst[ks * 4 + ni] = qbase[(kt * 8 + ks * 4) * N_DIM + ni * 16];
    };
    auto compute = [&](int b, const int* q, bool restart) {
        const char* AHb = (const char*)&AH[b][0];
        const char* ALb = (const char*)&AL[b][0];
#pragma unroll
        for (int ks = 0; ks < 2; ks++) {
            s8v bfr[4];
#pragma unroll
            for (int ni = 0; ni < 4; ni++)
                bfr[ni] = unpackB((unsigned int)q[ks * 4 + ni]);
            const int kb = (ks << 6) | fk16;
#pragma unroll
            for (int mi = 0; mi < 4; mi++) {
                const int r = wr + mi * 16 + frow;
                const int off = r * 128 + (kb ^ ((r & 7) << 4));
                s8v ah = *(const s8v*)(AHb + off);
                s8v al = *(const s8v*)(ALb + off);
#pragma unroll
                for (int ni = 0; ni < 4; ni++) {
                    f4v c0 = (restart && ks == 0) ? z4 : S[mi][ni];
                    S[mi][ni] = __builtin_amdgcn_mfma_f32_16x16x32_bf16(
                        ah, bfr[ni], c0, 0, 0, 0);
                    S[mi][ni] = __builtin_amdgcn_mfma_f32_16x16x32_bf16(
                        al, bfr[ni], S[mi][ni], 0, 0, 0);
                }
            }
        }
    };

    stage(0, 0);
    loadq(qcur, 0);
    __syncthreads();

#pragma unroll 1
    for (int g = 0; g < NGROUPS; ++g) {
        const int kt0 = g * 2;
        // ---- sub0 (buf0) ----
        stage(kt0 + 1, 1);
        loadq(qnxt, kt0 + 1);
        compute(0, qcur, true);
        __syncthreads();
        // ---- sub1 (buf1) ----
        if (g < NGROUPS - 1) {
            stage(kt0 + 2, 0);
            loadq(qcur, kt0 + 2);
        }
        // fold operands (issue early, consumed after compute)
        float sc[4];
        int zw[4];
        f4v rsv[4];
        const float* sp = scales + (size_t)g * N_DIM + qcol;
        const int* qzp = qz + g * 512 + (qcol >> 3);
        const float* rp = rs + (size_t)g * M_DIM + row00;
#pragma unroll
        for (int ni = 0; ni < 4; ni++) sc[ni] = sp[ni * 16];
#pragma unroll
        for (int ni = 0; ni < 4; ni++) zw[ni] = qzp[ni * 2];
#pragma unroll
        for (int mi = 0; mi < 4; mi++) rsv[mi] = *(const f4v*)(rp + mi * 16);

        compute(1, qnxt, false);

#pragma unroll
        for (int ni = 0; ni < 4; ni++) {
            const float zc2 = sc[ni] * (float)(129 + ((zw[ni] >> zsh) & 15));
#pragma unroll
            for (int mi = 0; mi < 4; mi++)
                acc[mi][ni] += sc[ni] * S[mi][ni] - zc2 * rsv[mi];
        }
        __syncthreads();
    }

    // epilogue: C layout col = lane&15, row = (lane>>4)*4 + reg
    const int col0 = bn + wc + frow;
#pragma unroll
    for (int ni = 0; ni < 4; ni++) {
        const float bv = bias[col0 + ni * 16];
#pragma unroll
        for (int mi = 0; mi < 4; mi++) {
            f4v v = acc[mi][ni];
#pragma unroll
            for (int r2 = 0; r2 < 4; r2++)
                out[(size_t)(row00 + mi * 16 + r2) * N_DIM + col0 + ni * 16] =
                    v[r2] + bv;
        }
    }
}

// ---------------- fallback (ws too small): naive but correct ----------------
__global__ __launch_bounds__(256) void naive_q4(
    const float* __restrict__ x, const int* __restrict__ qw,
    const int* __restrict__ qz, const float* __restrict__ scales,
    const float* __restrict__ bias, float* __restrict__ out) {
    const int n = (blockIdx.x & 63) * 64 + (threadIdx.x & 63);
    const int m = (blockIdx.x >> 6) * 4 + (threadIdx.x >> 6);
    const float* xr = x + (size_t)m * K_DIM;
    float acc = 0.f;
    for (int g = 0; g < NGROUPS; ++g) {
        const float s = scales[g * N_DIM + n];
        const int z = ((qz[g * 512 + (n >> 3)] >> ((n & 7) * 4)) & 15) + 1;
        float gs = 0.f;
        for (int kk = 0; kk < 16; ++kk) {
            const int q = qw[(g * 16 + kk) * N_DIM + n];
            const float* xp = xr + g * 128 + kk * 8;
#pragma unroll
            for (int j = 0; j < 8; j++)
                gs += xp[j] * (float)(((q >> (4 * j)) & 15) - z);
        }
        acc += s * gs;
    }
    out[(size_t)m * N_DIM + n] = acc + bias[n];
}

extern "C" void kernel_launch(void* const* d_in, const int* in_sizes, int n_in,
                              void* d_out, int out_size, void* d_ws,
                              size_t ws_size, hipStream_t stream) {
    const float* x = (const float*)d_in[0];
    const int* qw = (const int*)d_in[1];
    const int* qz = (const int*)d_in[2];
    const float* sc = (const float*)d_in[3];
    const float* bias = (const float*)d_in[4];
    float* out = (float*)d_out;

    const size_t nel = (size_t)M_DIM * K_DIM;
    const size_t need = nel * 2 * sizeof(unsigned short) +
                        (size_t)NGROUPS * M_DIM * sizeof(float);  // 64.5 MB
    if (ws_size >= need) {
        unsigned short* xh = (unsigned short*)d_ws;
        unsigned short* xl = xh + nel;
        float* rs = (float*)(xl + nel);
        split_rs<<<M_DIM, 256, 0, stream>>>(x, xh, xl, rs);
        gemm_q4<<<(M_DIM / BM) * (N_DIM / BN), 256, 0, stream>>>(
            xh, xl, qw, qz, sc, rs, bias, out);
    } else {
        naive_q4<<<(M_DIM / 4) * (N_DIM / 64), 256, 0, stream>>>(x, qw, qz, sc,
                                                                 bias, out);
    }
}

// Round 4
// 308.917 us; speedup vs baseline: 1.3249x; 1.3249x over previous
//
#include <hip/hip_runtime.h>
#include <hip/hip_bf16.h>

// out[4096,4096] = x[4096,4096]fp32 @ dequant(int4 W)[4096,4096] + bias
// R3: single-bf16 x (round-to-nearest) + precomputed bf16 W'T.
//   W' = 128 + w  (exact bf16: 0x4300 + nibble), stored TRANSPOSED [n][k]
//   S_g = sum_{k in g} xhat[m,k] * W'[k,n]   (fp32 MFMA accum)
//   acc += s[g,n]*S_g - s[g,n]*(129+z[g,n]) * R_g[m],  R_g = rowsum of ROUNDED xhat.
// GEMM sync structure identical to R2 (verified): 2-phase double-buffered LDS,
// one __syncthreads per K-tile, glds staging with pre-swizzled source.

#define K_DIM 4096
#define N_DIM 4096
#define M_DIM 4096
#define BM 128
#define BN 128
#define BK 64
#define NGROUPS 32

typedef __attribute__((ext_vector_type(8))) short s8v;      // 8 bf16 = 4 VGPR
typedef __attribute__((ext_vector_type(4))) float f4v;
typedef __attribute__((ext_vector_type(4))) unsigned int u4v;
typedef __attribute__((ext_vector_type(2))) unsigned int u2v;
typedef __attribute__((ext_vector_type(4))) float float4v;

typedef __attribute__((address_space(3))) void LDSV;
typedef const __attribute__((address_space(1))) void GLBV;

__device__ __forceinline__ void glds16(const void* g, void* l) {
    __builtin_amdgcn_global_load_lds((GLBV*)g, (LDSV*)l, 16, 0, 0);
}

// nibble j of qq -> bf16(128+nib) halfword; two per dword, exact.
__device__ __forceinline__ u4v unpackB(unsigned int qq) {
    u4v d;
    d[0] = 0x43004300u + (qq & 15u) + ((qq & 0xF0u) << 12);
    d[1] = 0x43004300u + ((qq >> 8) & 15u) + ((qq & 0xF000u) << 4);
    d[2] = 0x43004300u + ((qq >> 16) & 15u) + ((qq & 0xF00000u) >> 4);
    d[3] = 0x43004300u + ((qq >> 24) & 15u) + ((qq >> 28) << 16);
    return d;
}

// ---- prologue A: x -> round-to-nearest bf16 + per-group rowsums of ROUNDED x
__global__ __launch_bounds__(256) void split_rs(const float* __restrict__ x,
                                                unsigned short* __restrict__ xh,
                                                float* __restrict__ rs) {
    const int m = blockIdx.x;
    const int tid = threadIdx.x;
    const size_t base = (size_t)m * K_DIM;
#pragma unroll
    for (int it = 0; it < 4; ++it) {
        const int i = it * 1024 + tid * 4;
        float4v v = *(const float4v*)(x + base + i);
        unsigned int hb[4];
        float s = 0.f;
#pragma unroll
        for (int j = 0; j < 4; j++) {
            unsigned int b = __float_as_uint(v[j]);
            unsigned int h = (b + 0x7FFFu + ((b >> 16) & 1u)) & 0xFFFF0000u;  // RNE
            hb[j] = h;
            s += __uint_as_float(h);   // rowsum of ROUNDED values (required!)
        }
        u2v hv = {(hb[0] >> 16) | hb[1], (hb[2] >> 16) | hb[3]};
        *(u2v*)(xh + base + i) = hv;
        // group = 128 floats = 32 consecutive threads (stays in one 32-lane half)
        s += __shfl_xor(s, 1);
        s += __shfl_xor(s, 2);
        s += __shfl_xor(s, 4);
        s += __shfl_xor(s, 8);
        s += __shfl_xor(s, 16);
        if ((tid & 31) == 0) rs[(size_t)(it * 8 + (tid >> 5)) * M_DIM + m] = s;
    }
}

// ---- prologue B: qweight -> bf16 (128+w), transposed to [n][k] -------------
__global__ __launch_bounds__(256) void dequantW(const int* __restrict__ qw,
                                                unsigned short* __restrict__ wt) {
    // block covers 8 kk (=64 k) x 32 n; tid: kk_loc = tid&7, n_loc = tid>>3
    const int b = blockIdx.x;            // 64 kk-blocks x 128 n-blocks
    const int kk = (b & 63) * 8 + (threadIdx.x & 7);
    const int n = (b >> 6) * 32 + (threadIdx.x >> 3);
    const unsigned int q = (unsigned int)qw[kk * N_DIM + n];
    u4v d = unpackB(q);
    *(u4v*)(wt + (size_t)n * K_DIM + kk * 8) = d;  // 8 consecutive k, 16B store
}

// ---------------- main GEMM --------------------------------------------------
__global__ __launch_bounds__(256, 2) void gemm_q4(
    const unsigned short* __restrict__ xh, const unsigned short* __restrict__ wt,
    const int* __restrict__ qz, const float* __restrict__ scales,
    const float* __restrict__ rs, const float* __restrict__ bias,
    float* __restrict__ out) {
    __shared__ __align__(16) unsigned short AH[2][BM * BK];  // 32 KB
    __shared__ __align__(16) unsigned short BT[2][BN * BK];  // 32 KB

    const int tid = threadIdx.x;
    const int lane = tid & 63;
    const int wid = tid >> 6;

    // bijective XCD swizzle (1024 wgs, 8 XCDs)
    const int bid = blockIdx.x;
    const int wg = ((bid & 7) << 7) + (bid >> 3);
    const int bm = (wg >> 5) << 7;
    const int bn = (wg & 31) << 7;

    const int wr = ((wid >> 1) & 1) << 6;
    const int wc = (wid & 1) << 6;

    const f4v z4 = {0.f, 0.f, 0.f, 0.f};
    f4v acc[4][4];
    f4v S[4][4];
#pragma unroll
    for (int i = 0; i < 4; i++)
#pragma unroll
        for (int j = 0; j < 4; j++) acc[i][j] = z4;

    // ---- staging (glds, pre-swizzled source; verified pattern) ----
    const int arow = lane >> 3;
    const int aswz = ((lane & 7) ^ arow) << 3;
    const size_t a_gbase = (size_t)(bm + wid * 32 + arow) * K_DIM + aswz;
    const size_t b_gbase = (size_t)(bn + wid * 32 + arow) * K_DIM + aswz;

    // ---- fragment coords (16x16x32 bf16 MFMA) ----
    const int frow = lane & 15;
    const int fk16 = (lane >> 4) << 4;   // k byte offset within 64-elem row
    const int qcol = bn + wc + frow;     // ni=0 column
    const int zsh = (qcol & 7) * 4;
    const int row00 = bm + wr + ((lane >> 4) << 2);

    auto stage = [&](int kt, int b) {
        const unsigned short* ga = xh + a_gbase + kt * BK;
        const unsigned short* gb = wt + b_gbase + kt * BK;
        unsigned short* ad = &AH[b][(wid * 32) * BK];
        unsigned short* bd = &BT[b][(wid * 32) * BK];
#pragma unroll
        for (int i = 0; i < 4; i++) {
            glds16(ga + i * 8 * K_DIM, ad + i * 8 * BK);
            glds16(gb + i * 8 * K_DIM, bd + i * 8 * BK);
        }
    };
    auto compute = [&](int b, bool restart) {
        const char* Ab = (const char*)&AH[b][0];
        const char* Bb = (const char*)&BT[b][0];
#pragma unroll
        for (int ks = 0; ks < 2; ks++) {
            const int kb = (ks << 6) | fk16;
            s8v bfr[4];
#pragma unroll
            for (int ni = 0; ni < 4; ni++) {
                const int r = wc + ni * 16 + frow;
                bfr[ni] = *(const s8v*)(Bb + r * 128 + (kb ^ ((r & 7) << 4)));
            }
#pragma unroll
            for (int mi = 0; mi < 4; mi++) {
                const int r = wr + mi * 16 + frow;
                s8v ah = *(const s8v*)(Ab + r * 128 + (kb ^ ((r & 7) << 4)));
#pragma unroll
                for (int ni = 0; ni < 4; ni++) {
                    f4v c0 = (restart && ks == 0) ? z4 : S[mi][ni];
                    S[mi][ni] = __builtin_amdgcn_mfma_f32_16x16x32_bf16(
                        ah, bfr[ni], c0, 0, 0, 0);
                }
            }
        }
    };

    stage(0, 0);
    __syncthreads();

#pragma unroll 1
    for (int g = 0; g < NGROUPS; ++g) {
        const int kt0 = g * 2;
        // ---- sub0 (buf0) ----
        stage(kt0 + 1, 1);
        compute(0, true);
        __syncthreads();
        // ---- sub1 (buf1) ----
        if (g < NGROUPS - 1) stage(kt0 + 2, 0);
        // fold operands (issued early, consumed after compute)
        float sc[4];
        int zw[4];
        f4v rsv[4];
        const float* sp = scales + (size_t)g * N_DIM + qcol;
        const int* qzp = qz + g * 512 + (qcol >> 3);
        const float* rp = rs + (size_t)g * M_DIM + row00;
#pragma unroll
        for (int ni = 0; ni < 4; ni++) sc[ni] = sp[ni * 16];
#pragma unroll
        for (int ni = 0; ni < 4; ni++) zw[ni] = qzp[ni * 2];
#pragma unroll
        for (int mi = 0; mi < 4; mi++) rsv[mi] = *(const f4v*)(rp + mi * 16);

        compute(1, false);

#pragma unroll
        for (int ni = 0; ni < 4; ni++) {
            const float zc2 = sc[ni] * (float)(129 + ((zw[ni] >> zsh) & 15));
#pragma unroll
            for (int mi = 0; mi < 4; mi++)
                acc[mi][ni] += sc[ni] * S[mi][ni] - zc2 * rsv[mi];
        }
        __syncthreads();
    }

    // epilogue: C layout col = lane&15, row = (lane>>4)*4 + reg
    const int col0 = bn + wc + frow;
#pragma unroll
    for (int ni = 0; ni < 4; ni++) {
        const float bv = bias[col0 + ni * 16];
#pragma unroll
        for (int mi = 0; mi < 4; mi++) {
            f4v v = acc[mi][ni];
#pragma unroll
            for (int r2 = 0; r2 < 4; r2++)
                out[(size_t)(row00 + mi * 16 + r2) * N_DIM + col0 + ni * 16] =
                    v[r2] + bv;
        }
    }
}

// ---------------- fallback (ws too small): naive but correct ----------------
__global__ __launch_bounds__(256) void naive_q4(
    const float* __restrict__ x, const int* __restrict__ qw,
    const int* __restrict__ qz, const float* __restrict__ scales,
    const float* __restrict__ bias, float* __restrict__ out) {
    const int n = (blockIdx.x & 63) * 64 + (threadIdx.x & 63);
    const int m = (blockIdx.x >> 6) * 4 + (threadIdx.x >> 6);
    const float* xr = x + (size_t)m * K_DIM;
    float acc = 0.f;
    for (int g = 0; g < NGROUPS; ++g) {
        const float s = scales[g * N_DIM + n];
        const int z = ((qz[g * 512 + (n >> 3)] >> ((n & 7) * 4)) & 15) + 1;
        float gs = 0.f;
        for (int kk = 0; kk < 16; ++kk) {
            const int q = qw[(g * 16 + kk) * N_DIM + n];
            const float* xp = xr + g * 128 + kk * 8;
#pragma unroll
            for (int j = 0; j < 8; j++)
                gs += xp[j] * (float)(((q >> (4 * j)) & 15) - z);
        }
        acc += s * gs;
    }
    out[(size_t)m * N_DIM + n] = acc + bias[n];
}

extern "C" void kernel_launch(void* const* d_in, const int* in_sizes, int n_in,
                              void* d_out, int out_size, void* d_ws,
                              size_t ws_size, hipStream_t stream) {
    const float* x = (const float*)d_in[0];
    const int* qw = (const int*)d_in[1];
    const int* qz = (const int*)d_in[2];
    const float* sc = (const float*)d_in[3];
    const float* bias = (const float*)d_in[4];
    float* out = (float*)d_out;

    const size_t nel = (size_t)M_DIM * K_DIM;
    // xh (32MB) + rs (0.5MB) + wt (32MB) = same 64.5MB footprint as R2
    const size_t need = nel * sizeof(unsigned short) +
                        (size_t)NGROUPS * M_DIM * sizeof(float) +
                        nel * sizeof(unsigned short);
    if (ws_size >= need) {
        unsigned short* xh = (unsigned short*)d_ws;
        float* rsp = (float*)(xh + nel);
        unsigned short* wtp = (unsigned short*)(rsp + (size_t)NGROUPS * M_DIM);
        split_rs<<<M_DIM, 256, 0, stream>>>(x, xh, rsp);
        dequantW<<<64 * 128, 256, 0, stream>>>(qw, wtp);
        gemm_q4<<<(M_DIM / BM) * (N_DIM / BN), 256, 0, stream>>>(
            xh, wtp, qz, sc, rsp, bias, out);
    } else {
        naive_q4<<<(M_DIM / 4) * (N_DIM / 64), 256, 0, stream>>>(x, qw, qz, sc,
                                                                 bias, out);
    }
}

// Round 6
// 272.280 us; speedup vs baseline: 1.5032x; 1.1346x over previous
//
#include <hip/hip_runtime.h>
#include <hip/hip_bf16.h>

// out[4096,4096] = x[4096,4096]fp32 @ dequant(int4 W)[4096,4096] + bias
// R5: FULL dequant precompute — wt[n][k] = bf16_rne(s[g,n]*(w[k,n]-z[g,n]-1)).
//     x -> bf16 RNE (castx). GEMM = plain bf16 MFMA GEMM + bias, on the
//     verified R4 2-phase double-buffered skeleton (one __syncthreads/tile,
//     glds staging, pre-swizzled source, XOR-swizzled ds_read_b128).
//     No group structure in the hot loop at all.

#define K_DIM 4096
#define N_DIM 4096
#define M_DIM 4096
#define BM 128
#define BN 128
#define BK 64
#define NGROUPS 32

typedef __attribute__((ext_vector_type(8))) short s8v;      // 8 bf16 = 4 VGPR
typedef __attribute__((ext_vector_type(4))) float f4v;
typedef __attribute__((ext_vector_type(4))) unsigned int u4v;
typedef __attribute__((ext_vector_type(2))) unsigned int u2v;
typedef __attribute__((ext_vector_type(4))) float float4v;

typedef __attribute__((address_space(3))) void LDSV;
typedef const __attribute__((address_space(1))) void GLBV;

__device__ __forceinline__ void glds16(const void* g, void* l) {
    __builtin_amdgcn_global_load_lds((GLBV*)g, (LDSV*)l, 16, 0, 0);
}

__device__ __forceinline__ unsigned int bf16rne(float f) {
    unsigned int b = __float_as_uint(f);
    return (b + 0x7FFFu + ((b >> 16) & 1u)) >> 16;
}

// ---- prologue A: x -> round-to-nearest bf16 --------------------------------
__global__ __launch_bounds__(256) void castx(const float* __restrict__ x,
                                             unsigned short* __restrict__ xh,
                                             int n4) {
    int i0 = blockIdx.x * 256 + threadIdx.x;
    int st = gridDim.x * 256;
    for (int i = i0; i < n4; i += st) {
        float4v v = ((const float4v*)x)[i];
        unsigned int h[4];
#pragma unroll
        for (int j = 0; j < 4; j++) {
            unsigned int b = __float_as_uint(v[j]);
            h[j] = (b + 0x7FFFu + ((b >> 16) & 1u)) & 0xFFFF0000u;
        }
        u2v o = {(h[0] >> 16) | h[1], (h[2] >> 16) | h[3]};
        ((u2v*)xh)[i] = o;
    }
}

// ---- prologue B: full dequant, transposed [n][k], coalesced both sides -----
// grid 64 kkblk x 16 nblk; block: 8 kk-words x 256 n. LDS transpose 32KB.
__global__ __launch_bounds__(256) void dequantW(const int* __restrict__ qw,
                                                const int* __restrict__ qz,
                                                const float* __restrict__ scales,
                                                unsigned short* __restrict__ wt) {
    __shared__ __align__(16) unsigned short T[256 * 64];  // [n_loc][64 k] 32KB
    const int b = blockIdx.x;
    const int kkb = b & 63;        // 8 kk-words -> k in [kkb*64, kkb*64+64)
    const int nb = b >> 6;         // 256-col block
    const int tid = threadIdx.x;
    const int n = nb * 256 + tid;
    const int g = kkb >> 1;        // 64 k fits inside one group of 128
    const float s = scales[g * N_DIM + n];
    const int zp1 = ((qz[g * 512 + (n >> 3)] >> ((n & 7) * 4)) & 15) + 1;

    char* Tb = (char*)T;
#pragma unroll
    for (int r = 0; r < 8; r++) {
        const unsigned int q = (unsigned int)qw[(kkb * 8 + r) * N_DIM + n];
        unsigned int hw[8];
#pragma unroll
        for (int j = 0; j < 8; j++) {
            float v = s * (float)((int)((q >> (4 * j)) & 15u) - zp1);
            hw[j] = bf16rne(v);
        }
        u4v d = {hw[0] | (hw[1] << 16), hw[2] | (hw[3] << 16),
                 hw[4] | (hw[5] << 16), hw[6] | (hw[7] << 16)};
        *(u4v*)(Tb + tid * 128 + ((r * 16) ^ ((tid & 7) << 4))) = d;
    }
    __syncthreads();
    // write: 8 passes x (32 rows x 128B), coalesced 128B per row
#pragma unroll
    for (int p = 0; p < 8; p++) {
        const int nl = p * 32 + (tid >> 3);
        const int c = tid & 7;
        u4v d = *(const u4v*)(Tb + nl * 128 + ((c * 16) ^ ((nl & 7) << 4)));
        *(u4v*)(wt + (size_t)(nb * 256 + nl) * K_DIM + kkb * 64 + c * 8) = d;
    }
}

// ---------------- main GEMM: plain bf16, 2-phase dbuf ------------------------
__global__ __launch_bounds__(256, 2) void gemm_q4(
    const unsigned short* __restrict__ xh, const unsigned short* __restrict__ wt,
    const float* __restrict__ bias, float* __restrict__ out) {
    __shared__ __align__(16) unsigned short A[2][BM * BK];  // 32 KB
    __shared__ __align__(16) unsigned short B[2][BN * BK];  // 32 KB

    const int tid = threadIdx.x;
    const int lane = tid & 63;
    const int wid = tid >> 6;

    // bijective XCD swizzle (1024 wgs, 8 XCDs)
    const int bid = blockIdx.x;
    const int wg = ((bid & 7) << 7) + (bid >> 3);
    const int bm = (wg >> 5) << 7;
    const int bn = (wg & 31) << 7;

    const int wr = ((wid >> 1) & 1) << 6;
    const int wc = (wid & 1) << 6;

    const f4v z4 = {0.f, 0.f, 0.f, 0.f};
    f4v acc[4][4];
#pragma unroll
    for (int i = 0; i < 4; i++)
#pragma unroll
        for (int j = 0; j < 4; j++) acc[i][j] = z4;

    // staging (glds, pre-swizzled source; verified)
    const int arow = lane >> 3;
    const int aswz = ((lane & 7) ^ arow) << 3;
    const size_t a_gbase = (size_t)(bm + wid * 32 + arow) * K_DIM + aswz;
    const size_t b_gbase = (size_t)(bn + wid * 32 + arow) * K_DIM + aswz;

    // fragment coords (16x16x32 bf16 MFMA)
    const int frow = lane & 15;
    const int fk16 = (lane >> 4) << 4;
    const int row00 = bm + wr + ((lane >> 4) << 2);

    auto stage = [&](int kt, int b) {
        const unsigned short* ga = xh + a_gbase + kt * BK;
        const unsigned short* gb = wt + b_gbase + kt * BK;
        unsigned short* ad = &A[b][(wid * 32) * BK];
        unsigned short* bd = &B[b][(wid * 32) * BK];
#pragma unroll
        for (int i = 0; i < 4; i++) {
            glds16(ga + i * 8 * K_DIM, ad + i * 8 * BK);
            glds16(gb + i * 8 * K_DIM, bd + i * 8 * BK);
        }
    };
    auto compute = [&](int b) {
        const char* Ab = (const char*)&A[b][0];
        const char* Bb = (const char*)&B[b][0];
#pragma unroll
        for (int ks = 0; ks < 2; ks++) {
            const int kb = (ks << 6) | fk16;
            s8v bfr[4];
#pragma unroll
            for (int ni = 0; ni < 4; ni++) {
                const int r = wc + ni * 16 + frow;
                bfr[ni] = *(const s8v*)(Bb + r * 128 + (kb ^ ((r & 7) << 4)));
            }
#pragma unroll
            for (int mi = 0; mi < 4; mi++) {
                const int r = wr + mi * 16 + frow;
                s8v ah = *(const s8v*)(Ab + r * 128 + (kb ^ ((r & 7) << 4)));
#pragma unroll
                for (int ni = 0; ni < 4; ni++)
                    acc[mi][ni] = __builtin_amdgcn_mfma_f32_16x16x32_bf16(
                        ah, bfr[ni], acc[mi][ni], 0, 0, 0);
            }
        }
    };

    stage(0, 0);
    __syncthreads();

#pragma unroll 1
    for (int t = 0; t < 64; ++t) {
        if (t < 63) stage(t + 1, (t + 1) & 1);
        compute(t & 1);
        __syncthreads();
    }

    // epilogue: C layout col = lane&15, row = (lane>>4)*4 + reg
    const int col0 = bn + wc + frow;
#pragma unroll
    for (int ni = 0; ni < 4; ni++) {
        const float bv = bias[col0 + ni * 16];
#pragma unroll
        for (int mi = 0; mi < 4; mi++) {
            f4v v = acc[mi][ni];
#pragma unroll
            for (int r2 = 0; r2 < 4; r2++)
                out[(size_t)(row00 + mi * 16 + r2) * N_DIM + col0 + ni * 16] =
                    v[r2] + bv;
        }
    }
}

// ---------------- fallback (ws too small): naive but correct ----------------
__global__ __launch_bounds__(256) void naive_q4(
    const float* __restrict__ x, const int* __restrict__ qw,
    const int* __restrict__ qz, const float* __restrict__ scales,
    const float* __restrict__ bias, float* __restrict__ out) {
    const int n = (blockIdx.x & 63) * 64 + (threadIdx.x & 63);
    const int m = (blockIdx.x >> 6) * 4 + (threadIdx.x >> 6);
    const float* xr = x + (size_t)m * K_DIM;
    float acc = 0.f;
    for (int g = 0; g < NGROUPS; ++g) {
        const float s = scales[g * N_DIM + n];
        const int z = ((qz[g * 512 + (n >> 3)] >> ((n & 7) * 4)) & 15) + 1;
        float gs = 0.f;
        for (int kk = 0; kk < 16; ++kk) {
            const int q = qw[(g * 16 + kk) * N_DIM + n];
            const float* xp = xr + g * 128 + kk * 8;
#pragma unroll
            for (int j = 0; j < 8; j++)
                gs += xp[j] * (float)(((q >> (4 * j)) & 15) - z);
        }
        acc += s * gs;
    }
    out[(size_t)m * N_DIM + n] = acc + bias[n];
}

extern "C" void kernel_launch(void* const* d_in, const int* in_sizes, int n_in,
                              void* d_out, int out_size, void* d_ws,
                              size_t ws_size, hipStream_t stream) {
    const float* x = (const float*)d_in[0];
    const int* qw = (const int*)d_in[1];
    const int* qz = (const int*)d_in[2];
    const float* sc = (const float*)d_in[3];
    const float* bias = (const float*)d_in[4];
    float* out = (float*)d_out;

    const size_t nel = (size_t)M_DIM * K_DIM;
    const size_t need = nel * 2 * sizeof(unsigned short);  // xh 32MB + wt 32MB
    if (ws_size >= need) {
        unsigned short* xh = (unsigned short*)d_ws;
        unsigned short* wtp = xh + nel;
        castx<<<2048, 256, 0, stream>>>(x, xh, (int)(nel / 4));
        dequantW<<<64 * 16, 256, 0, stream>>>(qw, qz, sc, wtp);
        gemm_q4<<<(M_DIM / BM) * (N_DIM / BN), 256, 0, stream>>>(xh, wtp, bias,
                                                                 out);
    } else {
        naive_q4<<<(M_DIM / 4) * (N_DIM / 64), 256, 0, stream>>>(x, qw, qz, sc,
                                                                 bias, out);
    }
}

// Round 7
// 248.386 us; speedup vs baseline: 1.6478x; 1.0962x over previous
//
#include <hip/hip_runtime.h>
#include <hip/hip_bf16.h>

// out[4096,4096] = x[4096,4096]fp32 @ dequant(int4 W)[4096,4096] + bias
// R7: 8-phase 256x256 GEMM (T2+T3+T4+T5 per catalog), fed by verified R6
//     prologues: castx (x->bf16 RNE) and dequantW (wt[n][k] = bf16(s*(w-z-1))).
// Schedule: 8 waves (2Mx4N), BK=64, LDS 128KB (2 buf x (A 32KB + B 32KB)).
//   Phase = {ds_read C-quadrant frags | stage 1 half-tile | barrier |
//            lgkmcnt(0) | setprio(1) 16 MFMA setprio(0) | [vmcnt] | barrier}
//   Half-tiles defined by READ phase so every stage lands >=1 barrier after
//   the region's last read. vmcnt(6) at phases 3/7 (3 half-tiles in flight);
//   peeled last iteration uses vmcnt(0) (counted-wait underflow guard).

#define K_DIM 4096
#define N_DIM 4096
#define M_DIM 4096
#define BM 256
#define BN 256
#define BK 64
#define NGROUPS 32

typedef __attribute__((ext_vector_type(8))) short s8v;      // 8 bf16 = 4 VGPR
typedef __attribute__((ext_vector_type(4))) float f4v;
typedef __attribute__((ext_vector_type(4))) unsigned int u4v;
typedef __attribute__((ext_vector_type(2))) unsigned int u2v;
typedef __attribute__((ext_vector_type(4))) float float4v;

typedef __attribute__((address_space(3))) void LDSV;
typedef const __attribute__((address_space(1))) void GLBV;

__device__ __forceinline__ void glds16(const void* g, void* l) {
    __builtin_amdgcn_global_load_lds((GLBV*)g, (LDSV*)l, 16, 0, 0);
}

__device__ __forceinline__ unsigned int bf16rne(float f) {
    unsigned int b = __float_as_uint(f);
    return (b + 0x7FFFu + ((b >> 16) & 1u)) >> 16;
}

// ---- prologue A: x -> round-to-nearest bf16 (verified R6) ------------------
__global__ __launch_bounds__(256) void castx(const float* __restrict__ x,
                                             unsigned short* __restrict__ xh,
                                             int n4) {
    int i0 = blockIdx.x * 256 + threadIdx.x;
    int st = gridDim.x * 256;
    for (int i = i0; i < n4; i += st) {
        float4v v = ((const float4v*)x)[i];
        unsigned int h[4];
#pragma unroll
        for (int j = 0; j < 4; j++) {
            unsigned int b = __float_as_uint(v[j]);
            h[j] = (b + 0x7FFFu + ((b >> 16) & 1u)) & 0xFFFF0000u;
        }
        u2v o = {(h[0] >> 16) | h[1], (h[2] >> 16) | h[3]};
        ((u2v*)xh)[i] = o;
    }
}

// ---- prologue B: full dequant, transposed [n][k] (verified R6) -------------
__global__ __launch_bounds__(256) void dequantW(const int* __restrict__ qw,
                                                const int* __restrict__ qz,
                                                const float* __restrict__ scales,
                                                unsigned short* __restrict__ wt) {
    __shared__ __align__(16) unsigned short T[256 * 64];
    const int b = blockIdx.x;
    const int kkb = b & 63;
    const int nb = b >> 6;
    const int tid = threadIdx.x;
    const int n = nb * 256 + tid;
    const int g = kkb >> 1;
    const float s = scales[g * N_DIM + n];
    const int zp1 = ((qz[g * 512 + (n >> 3)] >> ((n & 7) * 4)) & 15) + 1;

    char* Tb = (char*)T;
#pragma unroll
    for (int r = 0; r < 8; r++) {
        const unsigned int q = (unsigned int)qw[(kkb * 8 + r) * N_DIM + n];
        unsigned int hw[8];
#pragma unroll
        for (int j = 0; j < 8; j++) {
            float v = s * (float)((int)((q >> (4 * j)) & 15u) - zp1);
            hw[j] = bf16rne(v);
        }
        u4v d = {hw[0] | (hw[1] << 16), hw[2] | (hw[3] << 16),
                 hw[4] | (hw[5] << 16), hw[6] | (hw[7] << 16)};
        *(u4v*)(Tb + tid * 128 + ((r * 16) ^ ((tid & 7) << 4))) = d;
    }
    __syncthreads();
#pragma unroll
    for (int p = 0; p < 8; p++) {
        const int nl = p * 32 + (tid >> 3);
        const int c = tid & 7;
        u4v d = *(const u4v*)(Tb + nl * 128 + ((c * 16) ^ ((nl & 7) << 4)));
        *(u4v*)(wt + (size_t)(nb * 256 + nl) * K_DIM + kkb * 64 + c * 8) = d;
    }
}

// ---------------- main GEMM: 256x256 tile, 8-phase schedule ------------------
#define STAGE_A(BUF, H, T)                                                    \
    {                                                                         \
        _Pragma("unroll") for (int j = 0; j < 2; j++) {                       \
            const int s_ = 2 * wid + j;                                       \
            const int rA = (s_ < 8) ? ((H) * 64 + s_ * 8)                     \
                                    : (128 + (H) * 64 + (s_ - 8) * 8);        \
            glds16(xh + (size_t)(bm + rA + (lane >> 3)) * K_DIM + (T)*BK +    \
                       aswz,                                                  \
                   &LDS_[BUF][0][(H)*8192 + s_ * 512]);                       \
        }                                                                     \
    }
#define STAGE_B(BUF, H, T)                                                    \
    {                                                                         \
        _Pragma("unroll") for (int j = 0; j < 2; j++) {                       \
            const int s_ = 2 * wid + j;                                       \
            const int cB = ((s_ >> 2) << 6) + ((H) << 5) + ((s_ & 3) << 3);   \
            glds16(wt + (size_t)(bn + cB + (lane >> 3)) * K_DIM + (T)*BK +    \
                       aswz,                                                  \
                   &LDS_[BUF][1][(H)*8192 + s_ * 512]);                       \
        }                                                                     \
    }
#define VM6 asm volatile("s_waitcnt vmcnt(6)" ::: "memory");
#define VM0 asm volatile("s_waitcnt vmcnt(0)" ::: "memory");
#define NOP ;

#define PHASE(BUF, QM, QN, STAGE_CODE, WAIT_CODE)                             \
    {                                                                         \
        if ((QN) == 0) {                                                      \
            const char* Ab = (const char*)&LDS_[BUF][0][(QM)*8192];           \
            _Pragma("unroll") for (int mi = 0; mi < 4; mi++) {                \
                const int pos = wr * 64 + mi * 16 + frow;                     \
                const int ro = pos * 128;                                     \
                const int sw = (pos & 7) << 4;                                \
                afr[mi][0] = *(const s8v*)(Ab + ro + (fk16 ^ sw));            \
                afr[mi][1] = *(const s8v*)(Ab + ro + ((64 | fk16) ^ sw));     \
            }                                                                 \
        }                                                                     \
        if ((QM) == 0) {                                                      \
            const char* Bb = (const char*)&LDS_[BUF][1][(QN)*8192];           \
            _Pragma("unroll") for (int ni = 0; ni < 2; ni++) {                \
                const int pos = wc * 32 + ni * 16 + frow;                     \
                const int ro = pos * 128;                                     \
                const int sw = (pos & 7) << 4;                                \
                bfr[QN][ni][0] = *(const s8v*)(Bb + ro + (fk16 ^ sw));        \
                bfr[QN][ni][1] = *(const s8v*)(Bb + ro + ((64 | fk16) ^ sw)); \
            }                                                                 \
        }                                                                     \
        STAGE_CODE                                                            \
        __builtin_amdgcn_s_barrier();                                         \
        asm volatile("s_waitcnt lgkmcnt(0)" ::: "memory");                    \
        __builtin_amdgcn_s_setprio(1);                                        \
        _Pragma("unroll") for (int mi = 0; mi < 4; mi++)                      \
            _Pragma("unroll") for (int ni = 0; ni < 2; ni++) {                \
            acc[(QM)*4 + mi][(QN)*2 + ni] =                                   \
                __builtin_amdgcn_mfma_f32_16x16x32_bf16(                      \
                    afr[mi][0], bfr[QN][ni][0],                               \
                    acc[(QM)*4 + mi][(QN)*2 + ni], 0, 0, 0);                  \
            acc[(QM)*4 + mi][(QN)*2 + ni] =                                   \
                __builtin_amdgcn_mfma_f32_16x16x32_bf16(                      \
                    afr[mi][1], bfr[QN][ni][1],                               \
                    acc[(QM)*4 + mi][(QN)*2 + ni], 0, 0, 0);                  \
        }                                                                     \
        __builtin_amdgcn_s_setprio(0);                                        \
        WAIT_CODE                                                             \
        __builtin_amdgcn_s_barrier();                                         \
    }

__global__ __launch_bounds__(512, 2) void gemm8(
    const unsigned short* __restrict__ xh, const unsigned short* __restrict__ wt,
    const float* __restrict__ bias, float* __restrict__ out) {
    // [buf][A/B][16384 halfwords = 32KB] -> 128 KB total
    __shared__ __align__(16) unsigned short LDS_[2][2][16384];

    const int tid = threadIdx.x;
    const int lane = tid & 63;
    const int wid = tid >> 6;   // 0..7
    const int wr = wid >> 2;    // 0..1  (wave row: 128 rows each)
    const int wc = wid & 3;     // 0..3  (wave col: 64 cols each)

    // bijective XCD swizzle: 256 wgs, 8 XCDs
    const int bid = blockIdx.x;
    const int wg = ((bid & 7) << 5) + (bid >> 3);
    const int bm = (wg >> 4) << 8;
    const int bn = (wg & 15) << 8;

    const int frow = lane & 15;
    const int fk16 = (lane >> 4) << 4;
    const int aswz = ((lane & 7) ^ (lane >> 3)) << 3;  // element offset

    const f4v z4 = {0.f, 0.f, 0.f, 0.f};
    f4v acc[8][4];
#pragma unroll
    for (int i = 0; i < 8; i++)
#pragma unroll
        for (int j = 0; j < 4; j++) acc[i][j] = z4;

    s8v afr[4][2];      // current A quadrant: [mi][ks]
    s8v bfr[2][2][2];   // [qn][ni][ks] (both n-halves alive)

    // prologue: t0 fully (buf0), t1 minus A-h1 (buf1); issue order matters.
    STAGE_A(0, 0, 0)
    STAGE_A(0, 1, 0)
    STAGE_B(0, 0, 0)
    STAGE_B(0, 1, 0)
    STAGE_A(1, 0, 1)
    STAGE_B(1, 0, 1)
    STAGE_B(1, 1, 1)
    VM6
    __builtin_amdgcn_s_barrier();

#pragma unroll 1
    for (int i = 0; i < 31; ++i) {
        const int t1 = 2 * i + 1, t2 = 2 * i + 2, t3 = 2 * i + 3;
        PHASE(0, 0, 0, STAGE_A(1, 1, t1), NOP)   // completes t1
        PHASE(0, 0, 1, STAGE_A(0, 0, t2), NOP)
        PHASE(0, 1, 0, STAGE_B(0, 0, t2), NOP)
        PHASE(0, 1, 1, STAGE_B(0, 1, t2), VM6)   // t1 fully landed
        PHASE(1, 0, 0, STAGE_A(0, 1, t2), NOP)   // completes t2
        PHASE(1, 0, 1, STAGE_A(1, 0, t3), NOP)
        PHASE(1, 1, 0, STAGE_B(1, 0, t3), NOP)
        PHASE(1, 1, 1, STAGE_B(1, 1, t3), VM6)   // t2 fully landed
    }
    // peeled last iteration: tiles 62 (buf0), 63 (buf1); no further staging
    PHASE(0, 0, 0, STAGE_A(1, 1, 63), NOP)
    PHASE(0, 0, 1, NOP, NOP)
    PHASE(0, 1, 0, NOP, NOP)
    PHASE(0, 1, 1, NOP, VM0)                     // t63 fully landed
    PHASE(1, 0, 0, NOP, NOP)
    PHASE(1, 0, 1, NOP, NOP)
    PHASE(1, 1, 0, NOP, NOP)
    PHASE(1, 1, 1, NOP, NOP)

    // epilogue: C layout col = lane&15, row = (lane>>4)*4 + r2
    const int row0 = bm + wr * 128 + ((lane >> 4) << 2);
    const int col0 = bn + wc * 64 + frow;
#pragma unroll
    for (int n = 0; n < 4; n++) {
        const int cn = col0 + (n >> 1) * 32 + (n & 1) * 16;
        const float bv = bias[cn];
#pragma unroll
        for (int m = 0; m < 8; m++) {
            const int rm = row0 + (m >> 2) * 64 + (m & 3) * 16;
            f4v v = acc[m][n];
#pragma unroll
            for (int r2 = 0; r2 < 4; r2++)
                out[(size_t)(rm + r2) * N_DIM + cn] = v[r2] + bv;
        }
    }
}

// ---------------- fallback (ws too small): naive but correct ----------------
__global__ __launch_bounds__(256) void naive_q4(
    const float* __restrict__ x, const int* __restrict__ qw,
    const int* __restrict__ qz, const float* __restrict__ scales,
    const float* __restrict__ bias, float* __restrict__ out) {
    const int n = (blockIdx.x & 63) * 64 + (threadIdx.x & 63);
    const int m = (blockIdx.x >> 6) * 4 + (threadIdx.x >> 6);
    const float* xr = x + (size_t)m * K_DIM;
    float acc = 0.f;
    for (int g = 0; g < NGROUPS; ++g) {
        const float s = scales[g * N_DIM + n];
        const int z = ((qz[g * 512 + (n >> 3)] >> ((n & 7) * 4)) & 15) + 1;
        float gs = 0.f;
        for (int kk = 0; kk < 16; ++kk) {
            const int q = qw[(g * 16 + kk) * N_DIM + n];
            const float* xp = xr + g * 128 + kk * 8;
#pragma unroll
            for (int j = 0; j < 8; j++)
                gs += xp[j] * (float)(((q >> (4 * j)) & 15) - z);
        }
        acc += s * gs;
    }
    out[(size_t)m * N_DIM + n] = acc + bias[n];
}

extern "C" void kernel_launch(void* const* d_in, const int* in_sizes, int n_in,
                              void* d_out, int out_size, void* d_ws,
                              size_t ws_size, hipStream_t stream) {
    const float* x = (const float*)d_in[0];
    const int* qw = (const int*)d_in[1];
    const int* qz = (const int*)d_in[2];
    const float* sc = (const float*)d_in[3];
    const float* bias = (const float*)d_in[4];
    float* out = (float*)d_out;

    const size_t nel = (size_t)M_DIM * K_DIM;
    const size_t need = nel * 2 * sizeof(unsigned short);  // xh 32MB + wt 32MB
    if (ws_size >= need) {
        unsigned short* xh = (unsigned short*)d_ws;
        unsigned short* wtp = xh + nel;
        castx<<<2048, 256, 0, stream>>>(x, xh, (int)(nel / 4));
        dequantW<<<64 * 16, 256, 0, stream>>>(qw, qz, sc, wtp);
        gemm8<<<(M_DIM / BM) * (N_DIM / BN), 512, 0, stream>>>(xh, wtp, bias,
                                                               out);
    } else {
        naive_q4<<<(M_DIM / 4) * (N_DIM / 64), 256, 0, stream>>>(x, qw, qz, sc,
                                                                 bias, out);
    }
}

// Round 8
// 246.188 us; speedup vs baseline: 1.6625x; 1.0089x over previous
//
#include <hip/hip_runtime.h>
#include <hip/hip_bf16.h>

// out[4096,4096] = x[4096,4096]fp32 @ dequant(int4 W)[4096,4096] + bias
// R8: R7's 8-phase 256x256 GEMM + zero-register ds_read pipelining:
//   - bfr[1] read moved into phase 1 (phases 2/4 become pure-MFMA, no lgkm)
//   - phase 1/3 MFMA clusters split 8+8 with the second read batch issued
//     under the first 8 MFMAs (compiler emits fine-grained lgkmcnt)
//   - staging schedule / vmcnt(6) discipline / barriers identical to R7
//   - castx + dequantW fused into one `prep` launch.

#define K_DIM 4096
#define N_DIM 4096
#define M_DIM 4096
#define BM 256
#define BN 256
#define BK 64
#define NGROUPS 32

typedef __attribute__((ext_vector_type(8))) short s8v;      // 8 bf16 = 4 VGPR
typedef __attribute__((ext_vector_type(4))) float f4v;
typedef __attribute__((ext_vector_type(4))) unsigned int u4v;
typedef __attribute__((ext_vector_type(2))) unsigned int u2v;
typedef __attribute__((ext_vector_type(4))) float float4v;

typedef __attribute__((address_space(3))) void LDSV;
typedef const __attribute__((address_space(1))) void GLBV;

__device__ __forceinline__ void glds16(const void* g, void* l) {
    __builtin_amdgcn_global_load_lds((GLBV*)g, (LDSV*)l, 16, 0, 0);
}

__device__ __forceinline__ unsigned int bf16rne(float f) {
    unsigned int b = __float_as_uint(f);
    return (b + 0x7FFFu + ((b >> 16) & 1u)) >> 16;
}

// ---- fused prologue: blocks [0,1024) dequant W'T; [1024,3072) cast x ------
__global__ __launch_bounds__(256) void prep(const float* __restrict__ x,
                                            unsigned short* __restrict__ xh,
                                            const int* __restrict__ qw,
                                            const int* __restrict__ qz,
                                            const float* __restrict__ scales,
                                            unsigned short* __restrict__ wt) {
    __shared__ __align__(16) unsigned short T[256 * 64];
    const int tid = threadIdx.x;
    if (blockIdx.x >= 1024) {
        // castx: x -> bf16 RNE
        const int n4 = (M_DIM * K_DIM) / 4;
        int i0 = (blockIdx.x - 1024) * 256 + tid;
        const int st = 2048 * 256;
        for (int i = i0; i < n4; i += st) {
            float4v v = ((const float4v*)x)[i];
            unsigned int h[4];
#pragma unroll
            for (int j = 0; j < 4; j++) {
                unsigned int b = __float_as_uint(v[j]);
                h[j] = (b + 0x7FFFu + ((b >> 16) & 1u)) & 0xFFFF0000u;
            }
            u2v o = {(h[0] >> 16) | h[1], (h[2] >> 16) | h[3]};
            ((u2v*)xh)[i] = o;
        }
        return;
    }
    // dequantW: wt[n][k] = bf16_rne(s*(w-z-1)), LDS-transposed, coalesced
    const int b = blockIdx.x;
    const int kkb = b & 63;
    const int nb = b >> 6;
    const int n = nb * 256 + tid;
    const int g = kkb >> 1;
    const float s = scales[g * N_DIM + n];
    const int zp1 = ((qz[g * 512 + (n >> 3)] >> ((n & 7) * 4)) & 15) + 1;

    char* Tb = (char*)T;
#pragma unroll
    for (int r = 0; r < 8; r++) {
        const unsigned int q = (unsigned int)qw[(kkb * 8 + r) * N_DIM + n];
        unsigned int hw[8];
#pragma unroll
        for (int j = 0; j < 8; j++) {
            float v = s * (float)((int)((q >> (4 * j)) & 15u) - zp1);
            hw[j] = bf16rne(v);
        }
        u4v d = {hw[0] | (hw[1] << 16), hw[2] | (hw[3] << 16),
                 hw[4] | (hw[5] << 16), hw[6] | (hw[7] << 16)};
        *(u4v*)(Tb + tid * 128 + ((r * 16) ^ ((tid & 7) << 4))) = d;
    }
    __syncthreads();
#pragma unroll
    for (int p = 0; p < 8; p++) {
        const int nl = p * 32 + (tid >> 3);
        const int c = tid & 7;
        u4v d = *(const u4v*)(Tb + nl * 128 + ((c * 16) ^ ((nl & 7) << 4)));
        *(u4v*)(wt + (size_t)(nb * 256 + nl) * K_DIM + kkb * 64 + c * 8) = d;
    }
}

// ---------------- main GEMM: 256x256 tile, 8-phase schedule ------------------
#define STAGE_A(BUF, H, T)                                                    \
    {                                                                         \
        _Pragma("unroll") for (int j = 0; j < 2; j++) {                       \
            const int s_ = 2 * wid + j;                                       \
            const int rA = (s_ < 8) ? ((H) * 64 + s_ * 8)                     \
                                    : (128 + (H) * 64 + (s_ - 8) * 8);        \
            glds16(xh + (size_t)(bm + rA + (lane >> 3)) * K_DIM + (T)*BK +    \
                       aswz,                                                  \
                   &LDS_[BUF][0][(H)*8192 + s_ * 512]);                       \
        }                                                                     \
    }
#define STAGE_B(BUF, H, T)                                                    \
    {                                                                         \
        _Pragma("unroll") for (int j = 0; j < 2; j++) {                       \
            const int s_ = 2 * wid + j;                                       \
            const int cB = ((s_ >> 2) << 6) + ((H) << 5) + ((s_ & 3) << 3);   \
            glds16(wt + (size_t)(bn + cB + (lane >> 3)) * K_DIM + (T)*BK +    \
                       aswz,                                                  \
                   &LDS_[BUF][1][(H)*8192 + s_ * 512]);                       \
        }                                                                     \
    }
#define RD_A2(BUF, QM, MI0)                                                   \
    {                                                                         \
        const char* Ab = (const char*)&LDS_[BUF][0][(QM)*8192];               \
        _Pragma("unroll") for (int mi = (MI0); mi < (MI0) + 2; mi++) {        \
            const int pos = wr * 64 + mi * 16 + frow;                         \
            const int ro = pos * 128;                                         \
            const int sw = (pos & 7) << 4;                                    \
            afr[mi][0] = *(const s8v*)(Ab + ro + (fk16 ^ sw));                \
            afr[mi][1] = *(const s8v*)(Ab + ro + ((64 | fk16) ^ sw));         \
        }                                                                     \
    }
#define RD_B(BUF, H)                                                          \
    {                                                                         \
        const char* Bb = (const char*)&LDS_[BUF][1][(H)*8192];                \
        _Pragma("unroll") for (int ni = 0; ni < 2; ni++) {                    \
            const int pos = wc * 32 + ni * 16 + frow;                         \
            const int ro = pos * 128;                                         \
            const int sw = (pos & 7) << 4;                                    \
            bfr[H][ni][0] = *(const s8v*)(Bb + ro + (fk16 ^ sw));             \
            bfr[H][ni][1] = *(const s8v*)(Bb + ro + ((64 | fk16) ^ sw));      \
        }                                                                     \
    }
#define MM2(MI0, QM, QN)                                                      \
    _Pragma("unroll") for (int mi = (MI0); mi < (MI0) + 2; mi++)              \
        _Pragma("unroll") for (int ni = 0; ni < 2; ni++) {                    \
        acc[(QM)*4 + mi][(QN)*2 + ni] =                                       \
            __builtin_amdgcn_mfma_f32_16x16x32_bf16(                          \
                afr[mi][0], bfr[QN][ni][0], acc[(QM)*4 + mi][(QN)*2 + ni], 0, \
                0, 0);                                                        \
        acc[(QM)*4 + mi][(QN)*2 + ni] =                                       \
            __builtin_amdgcn_mfma_f32_16x16x32_bf16(                          \
                afr[mi][1], bfr[QN][ni][1], acc[(QM)*4 + mi][(QN)*2 + ni], 0, \
                0, 0);                                                        \
    }
#define VM6 asm volatile("s_waitcnt vmcnt(6)" ::: "memory");
#define VM0 asm volatile("s_waitcnt vmcnt(0)" ::: "memory");
#define BAR __builtin_amdgcn_s_barrier();
#define PRIO1 __builtin_amdgcn_s_setprio(1);
#define PRIO0 __builtin_amdgcn_s_setprio(0);

// one buf-pass (4 phases) with stage codes SC1..SC4 and final wait W4
#define BUFPASS(BUF, SC1, SC2, SC3, SC4, W4)                                  \
    RD_A2(BUF, 0, 0) RD_B(BUF, 0)                                             \
    SC1                                                                       \
    BAR                                                                       \
    PRIO1 MM2(0, 0, 0) PRIO0                                                  \
    RD_A2(BUF, 0, 2) RD_B(BUF, 1)                                             \
    PRIO1 MM2(2, 0, 0) PRIO0                                                  \
    BAR                                                                       \
    SC2                                                                       \
    BAR                                                                       \
    PRIO1 MM2(0, 0, 1) MM2(2, 0, 1) PRIO0                                     \
    BAR                                                                       \
    RD_A2(BUF, 1, 0)                                                          \
    SC3                                                                       \
    BAR                                                                       \
    PRIO1 MM2(0, 1, 0) PRIO0                                                  \
    RD_A2(BUF, 1, 2)                                                          \
    PRIO1 MM2(2, 1, 0) PRIO0                                                  \
    BAR                                                                       \
    SC4                                                                       \
    BAR                                                                       \
    PRIO1 MM2(0, 1, 1) MM2(2, 1, 1) PRIO0                                     \
    W4                                                                        \
    BAR

#define SNOP ;

__global__ __launch_bounds__(512, 2) void gemm8(
    const unsigned short* __restrict__ xh, const unsigned short* __restrict__ wt,
    const float* __restrict__ bias, float* __restrict__ out) {
    __shared__ __align__(16) unsigned short LDS_[2][2][16384];  // 128 KB

    const int tid = threadIdx.x;
    const int lane = tid & 63;
    const int wid = tid >> 6;   // 0..7
    const int wr = wid >> 2;    // 0..1
    const int wc = wid & 3;     // 0..3

    // bijective XCD swizzle: 256 wgs, 8 XCDs
    const int bid = blockIdx.x;
    const int wg = ((bid & 7) << 5) + (bid >> 3);
    const int bm = (wg >> 4) << 8;
    const int bn = (wg & 15) << 8;

    const int frow = lane & 15;
    const int fk16 = (lane >> 4) << 4;
    const int aswz = ((lane & 7) ^ (lane >> 3)) << 3;

    const f4v z4 = {0.f, 0.f, 0.f, 0.f};
    f4v acc[8][4];
#pragma unroll
    for (int i = 0; i < 8; i++)
#pragma unroll
        for (int j = 0; j < 4; j++) acc[i][j] = z4;

    s8v afr[4][2];      // current A quadrant fragments
    s8v bfr[2][2][2];   // [half][ni][ks] — both n-halves persist

    // prologue: t0 fully (buf0), t1 minus A-h1 (buf1)
    STAGE_A(0, 0, 0)
    STAGE_A(0, 1, 0)
    STAGE_B(0, 0, 0)
    STAGE_B(0, 1, 0)
    STAGE_A(1, 0, 1)
    STAGE_B(1, 0, 1)
    STAGE_B(1, 1, 1)
    VM6
    BAR

#pragma unroll 1
    for (int i = 0; i < 31; ++i) {
        const int t1 = 2 * i + 1, t2 = 2 * i + 2, t3 = 2 * i + 3;
        BUFPASS(0, STAGE_A(1, 1, t1), STAGE_A(0, 0, t2), STAGE_B(0, 0, t2),
                STAGE_B(0, 1, t2), VM6)
        BUFPASS(1, STAGE_A(0, 1, t2), STAGE_A(1, 0, t3), STAGE_B(1, 0, t3),
                STAGE_B(1, 1, t3), VM6)
    }
    // peel: t62 (buf0, stage last A-h1 of t63), t63 (buf1, no staging)
    BUFPASS(0, STAGE_A(1, 1, 63), SNOP, SNOP, SNOP, VM0)
    BUFPASS(1, SNOP, SNOP, SNOP, SNOP, SNOP)

    // epilogue: C layout col = lane&15, row = (lane>>4)*4 + r2
    const int row0 = bm + wr * 128 + ((lane >> 4) << 2);
    const int col0 = bn + wc * 64 + frow;
#pragma unroll
    for (int n = 0; n < 4; n++) {
        const int cn = col0 + (n >> 1) * 32 + (n & 1) * 16;
        const float bv = bias[cn];
#pragma unroll
        for (int m = 0; m < 8; m++) {
            const int rm = row0 + (m >> 2) * 64 + (m & 3) * 16;
            f4v v = acc[m][n];
#pragma unroll
            for (int r2 = 0; r2 < 4; r2++)
                out[(size_t)(rm + r2) * N_DIM + cn] = v[r2] + bv;
        }
    }
}

// ---------------- fallback (ws too small): naive but correct ----------------
__global__ __launch_bounds__(256) void naive_q4(
    const float* __restrict__ x, const int* __restrict__ qw,
    const int* __restrict__ qz, const float* __restrict__ scales,
    const float* __restrict__ bias, float* __restrict__ out) {
    const int n = (blockIdx.x & 63) * 64 + (threadIdx.x & 63);
    const int m = (blockIdx.x >> 6) * 4 + (threadIdx.x >> 6);
    const float* xr = x + (size_t)m * K_DIM;
    float acc = 0.f;
    for (int g = 0; g < NGROUPS; ++g) {
        const float s = scales[g * N_DIM + n];
        const int z = ((qz[g * 512 + (n >> 3)] >> ((n & 7) * 4)) & 15) + 1;
        float gs = 0.f;
        for (int kk = 0; kk < 16; ++kk) {
            const int q = qw[(g * 16 + kk) * N_DIM + n];
            const float* xp = xr + g * 128 + kk * 8;
#pragma unroll
            for (int j = 0; j < 8; j++)
                gs += xp[j] * (float)(((q >> (4 * j)) & 15) - z);
        }
        acc += s * gs;
    }
    out[(size_t)m * N_DIM + n] = acc + bias[n];
}

extern "C" void kernel_launch(void* const* d_in, const int* in_sizes, int n_in,
                              void* d_out, int out_size, void* d_ws,
                              size_t ws_size, hipStream_t stream) {
    const float* x = (const float*)d_in[0];
    const int* qw = (const int*)d_in[1];
    const int* qz = (const int*)d_in[2];
    const float* sc = (const float*)d_in[3];
    const float* bias = (const float*)d_in[4];
    float* out = (float*)d_out;

    const size_t nel = (size_t)M_DIM * K_DIM;
    const size_t need = nel * 2 * sizeof(unsigned short);  // xh 32MB + wt 32MB
    if (ws_size >= need) {
        unsigned short* xh = (unsigned short*)d_ws;
        unsigned short* wtp = xh + nel;
        prep<<<3072, 256, 0, stream>>>(x, xh, qw, qz, sc, wtp);
        gemm8<<<(M_DIM / BM) * (N_DIM / BN), 512, 0, stream>>>(xh, wtp, bias,
                                                               out);
    } else {
        naive_q4<<<(M_DIM / 4) * (N_DIM / 64), 256, 0, stream>>>(x, qw, qz, sc,
                                                                 bias, out);
    }
}